// Round 1
// baseline (1371.677 us; speedup 1.0000x reference)
//
#include <hip/hip_runtime.h>

// Problem constants (from reference)
#define INCH   128
#define HEADS1 8
#define HID1   16
#define C1     128   // HEADS1*HID1
#define C2     64
#define NEG_SLOPE 0.2f

__device__ __forceinline__ unsigned fmap(float f) {
  unsigned b = __float_as_uint(f);
  return (b & 0x80000000u) ? ~b : (b | 0x80000000u);
}
__device__ __forceinline__ float funmap(unsigned u) {
  unsigned b = (u & 0x80000000u) ? (u & 0x7FFFFFFFu) : ~u;
  return __uint_as_float(b);
}
__device__ __forceinline__ float lrelu(float v) { return v >= 0.f ? v : NEG_SLOPE * v; }

// ---------------- Layer 1 ----------------

// h1 = x @ W1  (one block of 128 threads per node); fused s1/d1 head reductions.
__global__ void gemm1_kernel(const float* __restrict__ x, const float* __restrict__ W1,
                             const float* __restrict__ a_src, const float* __restrict__ a_dst,
                             float* __restrict__ h1, float* __restrict__ s1, float* __restrict__ d1) {
  __shared__ float xs[INCH];
  const int n = blockIdx.x;
  const int j = threadIdx.x;          // 0..127  (output channel = head*16 + c)
  xs[j] = x[n * INCH + j];
  __syncthreads();
  float acc = 0.f;
#pragma unroll
  for (int k = 0; k < INCH; ++k) acc += xs[k] * W1[k * C1 + j];
  h1[n * C1 + j] = acc;
  const int h = j >> 4;               // head 0..7
  const int c = j & 15;
  float sv = acc * a_src[h * HID1 + c];
  float dv = acc * a_dst[h * HID1 + c];
#pragma unroll
  for (int off = 8; off; off >>= 1) {
    sv += __shfl_down(sv, off, 16);
    dv += __shfl_down(dv, off, 16);
  }
  if (c == 0) { s1[n * HEADS1 + h] = sv; d1[n * HEADS1 + h] = dv; }
}

__global__ void edge_max1(const int* __restrict__ src, const int* __restrict__ dst,
                          const float* __restrict__ s1, const float* __restrict__ d1,
                          unsigned* __restrict__ m1, int E) {
  int e = blockIdx.x * blockDim.x + threadIdx.x;
  if (e >= E) return;
  int s = src[e], d = dst[e];
#pragma unroll
  for (int h = 0; h < HEADS1; ++h) {
    float v = lrelu(s1[s * HEADS1 + h] + d1[d * HEADS1 + h]);
    atomicMax(&m1[d * HEADS1 + h], fmap(v));
  }
}

__global__ void edge_sum1(const int* __restrict__ src, const int* __restrict__ dst,
                          const float* __restrict__ s1, const float* __restrict__ d1,
                          const unsigned* __restrict__ m1, float* __restrict__ z1, int E) {
  int e = blockIdx.x * blockDim.x + threadIdx.x;
  if (e >= E) return;
  int s = src[e], d = dst[e];
#pragma unroll
  for (int h = 0; h < HEADS1; ++h) {
    float v = lrelu(s1[s * HEADS1 + h] + d1[d * HEADS1 + h]);
    float w = expf(v - funmap(m1[d * HEADS1 + h]));
    atomicAdd(&z1[d * HEADS1 + h], w);
  }
}

// one block (128 threads) per edge: out1[dst, j] += h1[src, j] * alpha[h(j)]
__global__ void edge_scatter1(const int* __restrict__ src, const int* __restrict__ dst,
                              const float* __restrict__ s1, const float* __restrict__ d1,
                              const unsigned* __restrict__ m1, const float* __restrict__ z1,
                              const float* __restrict__ h1, float* __restrict__ out1) {
  const int e = blockIdx.x;
  const int j = threadIdx.x;          // 0..127
  const int h = j >> 4;
  const int s = src[e], d = dst[e];
  float v = lrelu(s1[s * HEADS1 + h] + d1[d * HEADS1 + h]);
  float w = expf(v - funmap(m1[d * HEADS1 + h]));
  float alpha = w / (z1[d * HEADS1 + h] + 1e-16f);
  atomicAdd(&out1[d * C1 + j], h1[s * C1 + j] * alpha);
}

// x2 = elu(out1 + b1)  (written into the h1 buffer, which is dead by now)
__global__ void elu_bias1(const float* __restrict__ out1, const float* __restrict__ b1,
                          float* __restrict__ x2, int total) {
  int i = blockIdx.x * blockDim.x + threadIdx.x;
  if (i >= total) return;
  float v = out1[i] + b1[i & (C1 - 1)];
  x2[i] = v > 0.f ? v : expm1f(v);
}

// ---------------- Layer 2 ----------------

// h2 = x2 @ W2 (one block of 64 threads per node); fused s2/d2 full-wave reductions.
__global__ void gemm2_kernel(const float* __restrict__ x2, const float* __restrict__ W2,
                             const float* __restrict__ a_src, const float* __restrict__ a_dst,
                             float* __restrict__ h2, float* __restrict__ s2, float* __restrict__ d2) {
  __shared__ float xs[C1];
  const int n = blockIdx.x;
  const int j = threadIdx.x;          // 0..63
  xs[j] = x2[n * C1 + j];
  xs[j + 64] = x2[n * C1 + 64 + j];
  __syncthreads();
  float acc = 0.f;
#pragma unroll
  for (int k = 0; k < C1; ++k) acc += xs[k] * W2[k * C2 + j];
  h2[n * C2 + j] = acc;
  float sv = acc * a_src[j];
  float dv = acc * a_dst[j];
#pragma unroll
  for (int off = 32; off; off >>= 1) {
    sv += __shfl_down(sv, off);
    dv += __shfl_down(dv, off);
  }
  if (j == 0) { s2[n] = sv; d2[n] = dv; }
}

__global__ void edge_max2(const int* __restrict__ src, const int* __restrict__ dst,
                          const float* __restrict__ s2, const float* __restrict__ d2,
                          unsigned* __restrict__ m2, int E) {
  int e = blockIdx.x * blockDim.x + threadIdx.x;
  if (e >= E) return;
  float v = lrelu(s2[src[e]] + d2[dst[e]]);
  atomicMax(&m2[dst[e]], fmap(v));
}

__global__ void edge_sum2(const int* __restrict__ src, const int* __restrict__ dst,
                          const float* __restrict__ s2, const float* __restrict__ d2,
                          const unsigned* __restrict__ m2, float* __restrict__ z2, int E) {
  int e = blockIdx.x * blockDim.x + threadIdx.x;
  if (e >= E) return;
  float v = lrelu(s2[src[e]] + d2[dst[e]]);
  float w = expf(v - funmap(m2[dst[e]]));
  atomicAdd(&z2[dst[e]], w);
}

// one block (64 threads) per edge: out[dst, j] += h2[src, j] * alpha
__global__ void edge_scatter2(const int* __restrict__ src, const int* __restrict__ dst,
                              const float* __restrict__ s2, const float* __restrict__ d2,
                              const unsigned* __restrict__ m2, const float* __restrict__ z2,
                              const float* __restrict__ h2, float* __restrict__ out) {
  const int e = blockIdx.x;
  const int j = threadIdx.x;          // 0..63
  const int s = src[e], d = dst[e];
  float v = lrelu(s2[s] + d2[d]);
  float w = expf(v - funmap(m2[d]));
  float alpha = w / (z2[d] + 1e-16f);
  atomicAdd(&out[d * C2 + j], h2[s * C2 + j] * alpha);
}

// out[n, c] = b2[c]   (init; scatter2 accumulates on top)
__global__ void init_out(float* __restrict__ out, const float* __restrict__ b2, int total) {
  int i = blockIdx.x * blockDim.x + threadIdx.x;
  if (i >= total) return;
  out[i] = b2[i & (C2 - 1)];
}

extern "C" void kernel_launch(void* const* d_in, const int* in_sizes, int n_in,
                              void* d_out, int out_size, void* d_ws, size_t ws_size,
                              hipStream_t stream) {
  const float* x      = (const float*)d_in[0];
  const int*   ei     = (const int*)d_in[1];
  const float* W1     = (const float*)d_in[2];
  const float* a_src1 = (const float*)d_in[3];
  const float* a_dst1 = (const float*)d_in[4];
  const float* b1     = (const float*)d_in[5];
  const float* W2     = (const float*)d_in[6];
  const float* a_src2 = (const float*)d_in[7];
  const float* a_dst2 = (const float*)d_in[8];
  const float* b2     = (const float*)d_in[9];
  float* out = (float*)d_out;

  const int N = in_sizes[0] / INCH;
  const int E = in_sizes[1] / 2;
  const int* src = ei;
  const int* dst = ei + E;

  // Workspace layout (floats)
  float* ws = (float*)d_ws;
  float*    h1   = ws;                      // N*128   (later reused as x2)
  float*    out1 = h1 + (size_t)N * C1;     // N*128
  float*    s1   = out1 + (size_t)N * C1;   // N*8
  float*    d1   = s1 + (size_t)N * HEADS1; // N*8
  unsigned* m1   = (unsigned*)(d1 + (size_t)N * HEADS1); // N*8
  float*    z1   = (float*)(m1 + (size_t)N * HEADS1);    // N*8
  float*    h2   = z1 + (size_t)N * HEADS1; // N*64
  float*    s2   = h2 + (size_t)N * C2;     // N
  float*    d2   = s2 + N;                  // N
  unsigned* m2   = (unsigned*)(d2 + N);     // N
  float*    z2   = (float*)(m2 + N);        // N

  // Zero accumulators (mapped -inf == 0 for m1/m2)
  hipMemsetAsync(out1, 0, (size_t)N * C1 * 4, stream);
  hipMemsetAsync(m1, 0, (size_t)N * HEADS1 * 4, stream);
  hipMemsetAsync(z1, 0, (size_t)N * HEADS1 * 4, stream);
  hipMemsetAsync(m2, 0, (size_t)N * 4, stream);
  hipMemsetAsync(z2, 0, (size_t)N * 4, stream);

  const int EB = (E + 255) / 256;

  // Layer 1
  gemm1_kernel<<<N, C1, 0, stream>>>(x, W1, a_src1, a_dst1, h1, s1, d1);
  edge_max1<<<EB, 256, 0, stream>>>(src, dst, s1, d1, m1, E);
  edge_sum1<<<EB, 256, 0, stream>>>(src, dst, s1, d1, m1, z1, E);
  edge_scatter1<<<E, C1, 0, stream>>>(src, dst, s1, d1, m1, z1, h1, out1);
  elu_bias1<<<(N * C1 + 255) / 256, 256, 0, stream>>>(out1, b1, h1, N * C1);

  // Layer 2 (x2 lives in h1's buffer)
  gemm2_kernel<<<N, C2, 0, stream>>>(h1, W2, a_src2, a_dst2, h2, s2, d2);
  edge_max2<<<EB, 256, 0, stream>>>(src, dst, s2, d2, m2, E);
  edge_sum2<<<EB, 256, 0, stream>>>(src, dst, s2, d2, m2, z2, E);
  init_out<<<(N * C2 + 255) / 256, 256, 0, stream>>>(out, b2, N * C2);
  edge_scatter2<<<E, C2, 0, stream>>>(src, dst, s2, d2, m2, z2, h2, out);
}

// Round 2
// 456.856 us; speedup vs baseline: 3.0024x; 3.0024x over previous
//
#include <hip/hip_runtime.h>

#define INCH   128
#define HEADS1 8
#define HID1   16
#define C1     128   // HEADS1*HID1
#define C2     64
#define NEG_SLOPE 0.2f

__device__ __forceinline__ float lrelu(float v) { return v >= 0.f ? v : NEG_SLOPE * v; }

// ---------------- CSR build (by destination) ----------------

__global__ void hist_kernel(const int* __restrict__ dst, int* __restrict__ deg, int E) {
  int e = blockIdx.x * blockDim.x + threadIdx.x;
  if (e < E) atomicAdd(&deg[dst[e]], 1);
}

// single-block exclusive scan over N degrees -> row_start[0..N]
__global__ void scan_kernel(const int* __restrict__ deg, int* __restrict__ row_start, int N) {
  __shared__ int sums[256];
  const int t = threadIdx.x;
  const int chunk = (N + 255) / 256;
  const int lo = t * chunk, hi = min(lo + chunk, N);
  int s = 0;
  for (int i = lo; i < hi; ++i) s += deg[i];
  sums[t] = s;
  __syncthreads();
  for (int off = 1; off < 256; off <<= 1) {
    int v = (t >= off) ? sums[t - off] : 0;
    __syncthreads();
    sums[t] += v;
    __syncthreads();
  }
  int run = (t == 0) ? 0 : sums[t - 1];
  for (int i = lo; i < hi; ++i) { row_start[i] = run; run += deg[i]; }
  if (t == 255) row_start[N] = sums[255];
}

__global__ void fill_kernel(const int* __restrict__ src, const int* __restrict__ dst,
                            const int* __restrict__ row_start, int* __restrict__ cursor,
                            int* __restrict__ src_sorted, int E) {
  int e = blockIdx.x * blockDim.x + threadIdx.x;
  if (e >= E) return;
  int d = dst[e];
  int slot = row_start[d] + atomicAdd(&cursor[d], 1);
  src_sorted[slot] = src[e];
}

// ---------------- Layer 1 ----------------

// h1 = x @ W1, 4 nodes per 128-thread block (W1 columns reused 4x from registers).
__global__ void gemm1_kernel(const float* __restrict__ x, const float* __restrict__ W1,
                             const float* __restrict__ a_src, const float* __restrict__ a_dst,
                             float* __restrict__ h1, float* __restrict__ s1, float* __restrict__ d1,
                             int N) {
  __shared__ float xs[4][INCH];
  const int n0 = blockIdx.x * 4;
  const int j = threadIdx.x;  // 0..127
#pragma unroll
  for (int i = 0; i < 4; ++i) {
    int n = n0 + i;
    if (n < N) xs[i][j] = x[(size_t)n * INCH + j];
  }
  __syncthreads();
  float acc[4] = {0.f, 0.f, 0.f, 0.f};
  for (int k = 0; k < INCH; ++k) {
    float w = W1[k * C1 + j];
#pragma unroll
    for (int i = 0; i < 4; ++i) acc[i] += xs[i][k] * w;
  }
  const int h = j >> 4, c = j & 15;
  const float as = a_src[h * HID1 + c], ad = a_dst[h * HID1 + c];
#pragma unroll
  for (int i = 0; i < 4; ++i) {
    int n = n0 + i;
    if (n >= N) break;
    h1[(size_t)n * C1 + j] = acc[i];
    float sv = acc[i] * as, dv = acc[i] * ad;
#pragma unroll
    for (int off = 8; off; off >>= 1) {
      sv += __shfl_down(sv, off, 16);
      dv += __shfl_down(dv, off, 16);
    }
    if (c == 0) { s1[n * HEADS1 + h] = sv; d1[n * HEADS1 + h] = dv; }
  }
}

// One block (128 threads) per destination node: segment softmax + aggregate + bias + ELU.
__global__ void agg1_kernel(const int* __restrict__ row_start, const int* __restrict__ src_sorted,
                            const float* __restrict__ s1, const float* __restrict__ d1,
                            const float* __restrict__ h1, const float* __restrict__ b1,
                            float* __restrict__ x2) {
  const int n = blockIdx.x;
  const int j = threadIdx.x;  // 0..127
  const int h = j >> 4;
  const int lo = row_start[n], hi = row_start[n + 1];
  const float dv = d1[n * HEADS1 + h];
  float m = -INFINITY;
  for (int i = lo; i < hi; ++i) {
    int s = src_sorted[i];
    m = fmaxf(m, lrelu(s1[s * HEADS1 + h] + dv));
  }
  if (!isfinite(m)) m = 0.f;  // isolated node guard (matches reference)
  float z = 0.f, acc = 0.f;
  for (int i = lo; i < hi; ++i) {
    int s = src_sorted[i];
    float v = lrelu(s1[s * HEADS1 + h] + dv);
    float w = __expf(v - m);
    z += w;
    acc += w * h1[(size_t)s * C1 + j];
  }
  float o = acc / (z + 1e-16f) + b1[j];
  x2[(size_t)n * C1 + j] = o > 0.f ? o : expm1f(o);
}

// ---------------- Layer 2 ----------------

// h2 = x2 @ W2, 8 nodes per 64-thread block.
__global__ void gemm2_kernel(const float* __restrict__ x2, const float* __restrict__ W2,
                             const float* __restrict__ a_src, const float* __restrict__ a_dst,
                             float* __restrict__ h2, float* __restrict__ s2, float* __restrict__ d2,
                             int N) {
  __shared__ float xs[8][C1];
  const int n0 = blockIdx.x * 8;
  const int j = threadIdx.x;  // 0..63
#pragma unroll
  for (int r = 0; r < 8; ++r) {
    int n = n0 + r;
    if (n < N) {
      xs[r][j] = x2[(size_t)n * C1 + j];
      xs[r][j + 64] = x2[(size_t)n * C1 + 64 + j];
    }
  }
  __syncthreads();
  float acc[8] = {0.f};
  for (int k = 0; k < C1; ++k) {
    float w = W2[k * C2 + j];
#pragma unroll
    for (int r = 0; r < 8; ++r) acc[r] += xs[r][k] * w;
  }
  const float as = a_src[j], ad = a_dst[j];
#pragma unroll
  for (int r = 0; r < 8; ++r) {
    int n = n0 + r;
    if (n >= N) break;
    h2[(size_t)n * C2 + j] = acc[r];
    float sv = acc[r] * as, dv = acc[r] * ad;
#pragma unroll
    for (int off = 32; off; off >>= 1) {
      sv += __shfl_down(sv, off);
      dv += __shfl_down(dv, off);
    }
    if (j == 0) { s2[n] = sv; d2[n] = dv; }
  }
}

// One block (64 threads) per destination node.
__global__ void agg2_kernel(const int* __restrict__ row_start, const int* __restrict__ src_sorted,
                            const float* __restrict__ s2, const float* __restrict__ d2,
                            const float* __restrict__ h2, const float* __restrict__ b2,
                            float* __restrict__ out) {
  const int n = blockIdx.x;
  const int j = threadIdx.x;  // 0..63
  const int lo = row_start[n], hi = row_start[n + 1];
  const float dv = d2[n];
  float m = -INFINITY;
  for (int i = lo; i < hi; ++i) m = fmaxf(m, lrelu(s2[src_sorted[i]] + dv));
  if (!isfinite(m)) m = 0.f;
  float z = 0.f, acc = 0.f;
  for (int i = lo; i < hi; ++i) {
    int s = src_sorted[i];
    float v = lrelu(s2[s] + dv);
    float w = __expf(v - m);
    z += w;
    acc += w * h2[(size_t)s * C2 + j];
  }
  out[(size_t)n * C2 + j] = acc / (z + 1e-16f) + b2[j];
}

extern "C" void kernel_launch(void* const* d_in, const int* in_sizes, int n_in,
                              void* d_out, int out_size, void* d_ws, size_t ws_size,
                              hipStream_t stream) {
  const float* x      = (const float*)d_in[0];
  const int*   ei     = (const int*)d_in[1];
  const float* W1     = (const float*)d_in[2];
  const float* a_src1 = (const float*)d_in[3];
  const float* a_dst1 = (const float*)d_in[4];
  const float* b1     = (const float*)d_in[5];
  const float* W2     = (const float*)d_in[6];
  const float* a_src2 = (const float*)d_in[7];
  const float* a_dst2 = (const float*)d_in[8];
  const float* b2     = (const float*)d_in[9];
  float* out = (float*)d_out;

  const int N = in_sizes[0] / INCH;
  const int E = in_sizes[1] / 2;
  const int* src = ei;
  const int* dst = ei + E;

  // Workspace layout (fits in the 71.2 MB footprint round-1 already used)
  float* ws = (float*)d_ws;
  float* h1 = ws;                            // N*128
  float* x2 = h1 + (size_t)N * C1;           // N*128
  float* s1 = x2 + (size_t)N * C1;           // N*8
  float* d1 = s1 + (size_t)N * HEADS1;       // N*8
  float* h2 = d1 + (size_t)N * HEADS1;       // N*64
  float* s2 = h2 + (size_t)N * C2;           // N
  float* d2 = s2 + N;                        // N
  int* deg        = (int*)(d2 + N);          // N (reused as cursor)
  int* row_start  = deg + N;                 // N+1
  int* src_sorted = row_start + (N + 1);     // E

  const int EB = (E + 255) / 256;

  // CSR build
  hipMemsetAsync(deg, 0, (size_t)N * 4, stream);
  hist_kernel<<<EB, 256, 0, stream>>>(dst, deg, E);
  scan_kernel<<<1, 256, 0, stream>>>(deg, row_start, N);
  hipMemsetAsync(deg, 0, (size_t)N * 4, stream);  // reuse as cursor
  fill_kernel<<<EB, 256, 0, stream>>>(src, dst, row_start, deg, src_sorted, E);

  // Layer 1
  gemm1_kernel<<<(N + 3) / 4, C1, 0, stream>>>(x, W1, a_src1, a_dst1, h1, s1, d1, N);
  agg1_kernel<<<N, C1, 0, stream>>>(row_start, src_sorted, s1, d1, h1, b1, x2);

  // Layer 2
  gemm2_kernel<<<(N + 7) / 8, C2, 0, stream>>>(x2, W2, a_src2, a_dst2, h2, s2, d2, N);
  agg2_kernel<<<N, C2, 0, stream>>>(row_start, src_sorted, s2, d2, h2, b2, out);
}

// Round 3
// 384.977 us; speedup vs baseline: 3.5630x; 1.1867x over previous
//
#include <hip/hip_runtime.h>
#include <hip/hip_fp16.h>

#define INCH   128
#define HEADS1 8
#define HID1   16
#define C1     128   // HEADS1*HID1
#define C2     64
#define NEG_SLOPE 0.2f

__device__ __forceinline__ float lrelu(float v) { return v >= 0.f ? v : NEG_SLOPE * v; }

// ---------------- CSR build (by destination) ----------------

__global__ void hist_kernel(const int* __restrict__ dst, int* __restrict__ deg, int E) {
  int e = blockIdx.x * blockDim.x + threadIdx.x;
  if (e < E) atomicAdd(&deg[dst[e]], 1);
}

// single-block exclusive scan over N degrees -> row_start[0..N]
__global__ void scan_kernel(const int* __restrict__ deg, int* __restrict__ row_start, int N) {
  __shared__ int sums[1024];
  const int t = threadIdx.x;
  const int chunk = (N + 1023) / 1024;
  const int lo = t * chunk, hi = min(lo + chunk, N);
  int s = 0;
  for (int i = lo; i < hi; ++i) s += deg[i];
  sums[t] = s;
  __syncthreads();
  for (int off = 1; off < 1024; off <<= 1) {
    int v = (t >= off) ? sums[t - off] : 0;
    __syncthreads();
    sums[t] += v;
    __syncthreads();
  }
  int run = (t == 0) ? 0 : sums[t - 1];
  for (int i = lo; i < hi; ++i) { row_start[i] = run; run += deg[i]; }
  if (t == 1023) row_start[N] = sums[1023];
}

__global__ void fill_kernel(const int* __restrict__ src, const int* __restrict__ dst,
                            const int* __restrict__ row_start, int* __restrict__ cursor,
                            int* __restrict__ src_sorted, int E) {
  int e = blockIdx.x * blockDim.x + threadIdx.x;
  if (e >= E) return;
  int d = dst[e];
  int slot = row_start[d] + atomicAdd(&cursor[d], 1);
  src_sorted[slot] = src[e];
}

// ---------------- GEMMs (16 nodes per block, float4 LDS reads) ----------------

__global__ void gemm1_kernel(const float* __restrict__ x, const float* __restrict__ W1,
                             const float* __restrict__ a_src, const float* __restrict__ a_dst,
                             float* __restrict__ h1, float* __restrict__ s1, float* __restrict__ d1,
                             int N) {
  __shared__ float xs[16][INCH];
  const int n0 = blockIdx.x * 16;
  const int j = threadIdx.x;  // 0..127
#pragma unroll
  for (int i = 0; i < 16; ++i) {
    int n = n0 + i;
    if (n < N) xs[i][j] = x[(size_t)n * INCH + j];
  }
  __syncthreads();
  float acc[16];
#pragma unroll
  for (int i = 0; i < 16; ++i) acc[i] = 0.f;
  for (int k = 0; k < INCH; k += 4) {
    float w0 = W1[(k + 0) * C1 + j];
    float w1 = W1[(k + 1) * C1 + j];
    float w2 = W1[(k + 2) * C1 + j];
    float w3 = W1[(k + 3) * C1 + j];
#pragma unroll
    for (int i = 0; i < 16; ++i) {
      float4 xv = *(const float4*)&xs[i][k];
      acc[i] += xv.x * w0 + xv.y * w1 + xv.z * w2 + xv.w * w3;
    }
  }
  const int h = j >> 4, c = j & 15;
  const float as = a_src[h * HID1 + c], ad = a_dst[h * HID1 + c];
#pragma unroll
  for (int i = 0; i < 16; ++i) {
    int n = n0 + i;
    if (n >= N) break;
    h1[(size_t)n * C1 + j] = acc[i];
    float sv = acc[i] * as, dv = acc[i] * ad;
#pragma unroll
    for (int off = 8; off; off >>= 1) {
      sv += __shfl_down(sv, off, 16);
      dv += __shfl_down(dv, off, 16);
    }
    if (c == 0) { s1[n * HEADS1 + h] = sv; d1[n * HEADS1 + h] = dv; }
  }
}

__global__ void gemm2_kernel(const float* __restrict__ x2, const float* __restrict__ W2,
                             const float* __restrict__ a_src, const float* __restrict__ a_dst,
                             float* __restrict__ h2, float* __restrict__ s2, float* __restrict__ d2,
                             int N) {
  __shared__ float xs[16][C1];
  const int n0 = blockIdx.x * 16;
  const int j = threadIdx.x;  // 0..63
#pragma unroll
  for (int i = 0; i < 16; ++i) {
    int n = n0 + i;
    if (n < N) {
      xs[i][j] = x2[(size_t)n * C1 + j];
      xs[i][j + 64] = x2[(size_t)n * C1 + 64 + j];
    }
  }
  __syncthreads();
  float acc[16];
#pragma unroll
  for (int i = 0; i < 16; ++i) acc[i] = 0.f;
  for (int k = 0; k < C1; k += 4) {
    float w0 = W2[(k + 0) * C2 + j];
    float w1 = W2[(k + 1) * C2 + j];
    float w2v = W2[(k + 2) * C2 + j];
    float w3 = W2[(k + 3) * C2 + j];
#pragma unroll
    for (int i = 0; i < 16; ++i) {
      float4 xv = *(const float4*)&xs[i][k];
      acc[i] += xv.x * w0 + xv.y * w1 + xv.z * w2v + xv.w * w3;
    }
  }
  const float as = a_src[j], ad = a_dst[j];
#pragma unroll
  for (int i = 0; i < 16; ++i) {
    int n = n0 + i;
    if (n >= N) break;
    h2[(size_t)n * C2 + j] = acc[i];
    float sv = acc[i] * as, dv = acc[i] * ad;
#pragma unroll
    for (int off = 32; off; off >>= 1) {
      sv += __shfl_down(sv, off);
      dv += __shfl_down(dv, off);
    }
    if (j == 0) { s2[n] = sv; d2[n] = dv; }
  }
}

// ---------------- Attention weights (wave per node) ----------------

// d1z: read d-logit at entry, overwritten with z at exit (same slot, same wave -> safe).
__global__ void attn1_kernel(const int* __restrict__ row_start, const int* __restrict__ src_sorted,
                             const float* __restrict__ s1, float* d1z,
                             __half* __restrict__ wbuf, int N) {
  const int wave = threadIdx.x >> 6;
  const int n = blockIdx.x * 4 + wave;
  if (n >= N) return;
  const int lane = threadIdx.x & 63;
  const int le = lane >> 3, h = lane & 7;   // 8 edge-slots x 8 heads
  const int lo = row_start[n], hi = row_start[n + 1];
  const float dv = d1z[n * HEADS1 + h];
  float m = -INFINITY;
  for (int i = lo + le; i < hi; i += 8)
    m = fmaxf(m, lrelu(s1[src_sorted[i] * HEADS1 + h] + dv));
#pragma unroll
  for (int off = 8; off < 64; off <<= 1) m = fmaxf(m, __shfl_xor(m, off));
  if (!isfinite(m)) m = 0.f;
  float z = 0.f;
  for (int i = lo + le; i < hi; i += 8) {
    float w = __expf(lrelu(s1[src_sorted[i] * HEADS1 + h] + dv) - m);
    wbuf[(size_t)i * HEADS1 + h] = __float2half(w);
    z += w;
  }
#pragma unroll
  for (int off = 8; off < 64; off <<= 1) z += __shfl_xor(z, off);
  if (le == 0) d1z[n * HEADS1 + h] = z;
}

__global__ void attn2_kernel(const int* __restrict__ row_start, const int* __restrict__ src_sorted,
                             const float* __restrict__ s2, float* d2z,
                             __half* __restrict__ wbuf2, int N) {
  const int wave = threadIdx.x >> 6;
  const int n = blockIdx.x * 4 + wave;
  if (n >= N) return;
  const int lane = threadIdx.x & 63;
  const int lo = row_start[n], hi = row_start[n + 1];
  const float dv = d2z[n];
  float m = -INFINITY;
  for (int i = lo + lane; i < hi; i += 64)
    m = fmaxf(m, lrelu(s2[src_sorted[i]] + dv));
#pragma unroll
  for (int off = 1; off < 64; off <<= 1) m = fmaxf(m, __shfl_xor(m, off));
  if (!isfinite(m)) m = 0.f;
  float z = 0.f;
  for (int i = lo + lane; i < hi; i += 64) {
    float w = __expf(lrelu(s2[src_sorted[i]] + dv) - m);
    wbuf2[i] = __float2half(w);
    z += w;
  }
#pragma unroll
  for (int off = 1; off < 64; off <<= 1) z += __shfl_xor(z, off);
  if (lane == 0) d2z[n] = z;
}

// ---------------- Weighted aggregation (pure gather) ----------------

__global__ void agg1_kernel(const int* __restrict__ row_start, const int* __restrict__ src_sorted,
                            const __half* __restrict__ wbuf, const float* __restrict__ z1n,
                            const float* __restrict__ h1, const float* __restrict__ b1,
                            float* __restrict__ x2) {
  const int n = blockIdx.x;
  const int j = threadIdx.x;  // 0..127
  const int h = j >> 4;
  const int lo = row_start[n], hi = row_start[n + 1];
  const float zinv = 1.f / (z1n[n * HEADS1 + h] + 1e-16f);
  float acc = 0.f;
  int i = lo;
  for (; i + 4 <= hi; i += 4) {
    int s0 = src_sorted[i], s1i = src_sorted[i + 1], s2i = src_sorted[i + 2], s3i = src_sorted[i + 3];
    float w0 = __half2float(wbuf[(size_t)(i + 0) * HEADS1 + h]);
    float w1 = __half2float(wbuf[(size_t)(i + 1) * HEADS1 + h]);
    float w2 = __half2float(wbuf[(size_t)(i + 2) * HEADS1 + h]);
    float w3 = __half2float(wbuf[(size_t)(i + 3) * HEADS1 + h]);
    acc += w0 * h1[(size_t)s0 * C1 + j];
    acc += w1 * h1[(size_t)s1i * C1 + j];
    acc += w2 * h1[(size_t)s2i * C1 + j];
    acc += w3 * h1[(size_t)s3i * C1 + j];
  }
  for (; i < hi; ++i)
    acc += __half2float(wbuf[(size_t)i * HEADS1 + h]) * h1[(size_t)src_sorted[i] * C1 + j];
  float o = acc * zinv + b1[j];
  x2[(size_t)n * C1 + j] = o > 0.f ? o : expm1f(o);
}

__global__ void agg2_kernel(const int* __restrict__ row_start, const int* __restrict__ src_sorted,
                            const __half* __restrict__ wbuf2, const float* __restrict__ z2n,
                            const float* __restrict__ h2, const float* __restrict__ b2,
                            float* __restrict__ out) {
  const int n = blockIdx.x;
  const int j = threadIdx.x;  // 0..63
  const int lo = row_start[n], hi = row_start[n + 1];
  const float zinv = 1.f / (z2n[n] + 1e-16f);
  float acc = 0.f;
  int i = lo;
  for (; i + 4 <= hi; i += 4) {
    int s0 = src_sorted[i], s1i = src_sorted[i + 1], s2i = src_sorted[i + 2], s3i = src_sorted[i + 3];
    float w0 = __half2float(wbuf2[i + 0]);
    float w1 = __half2float(wbuf2[i + 1]);
    float w2 = __half2float(wbuf2[i + 2]);
    float w3 = __half2float(wbuf2[i + 3]);
    acc += w0 * h2[(size_t)s0 * C2 + j];
    acc += w1 * h2[(size_t)s1i * C2 + j];
    acc += w2 * h2[(size_t)s2i * C2 + j];
    acc += w3 * h2[(size_t)s3i * C2 + j];
  }
  for (; i < hi; ++i)
    acc += __half2float(wbuf2[i]) * h2[(size_t)src_sorted[i] * C2 + j];
  out[(size_t)n * C2 + j] = acc * zinv + b2[j];
}

extern "C" void kernel_launch(void* const* d_in, const int* in_sizes, int n_in,
                              void* d_out, int out_size, void* d_ws, size_t ws_size,
                              hipStream_t stream) {
  const float* x      = (const float*)d_in[0];
  const int*   ei     = (const int*)d_in[1];
  const float* W1     = (const float*)d_in[2];
  const float* a_src1 = (const float*)d_in[3];
  const float* a_dst1 = (const float*)d_in[4];
  const float* b1     = (const float*)d_in[5];
  const float* W2     = (const float*)d_in[6];
  const float* a_src2 = (const float*)d_in[7];
  const float* a_dst2 = (const float*)d_in[8];
  const float* b2     = (const float*)d_in[9];
  float* out = (float*)d_out;

  const int N = in_sizes[0] / INCH;
  const int E = in_sizes[1] / 2;
  const int* src = ei;
  const int* dst = ei + E;

  // Workspace layout (~65 MB total; round-1 proved >=71 MB available)
  float* ws = (float*)d_ws;
  size_t o = 0;
  float* h1 = ws + o;            o += (size_t)N * C1;       // layer-1 features
  float* x2 = ws + o;            o += (size_t)N * C1;       // layer-2 input
  float* s1 = ws + o;            o += (size_t)N * HEADS1;
  float* d1 = ws + o;            o += (size_t)N * HEADS1;   // becomes z1 after attn1
  __half* wbuf = (__half*)(ws + o); o += (size_t)E * HEADS1 / 2;  // E*8 halves
  int* deg        = (int*)(ws + o); o += N;                 // reused as cursor
  int* row_start  = (int*)(ws + o); o += N + 1;
  int* src_sorted = (int*)(ws + o); o += E;
  // layer-2 aliases into h1's region (h1 dead after agg1)
  float* h2 = h1;                          // N*64
  float* s2 = h1 + (size_t)N * C2;         // N
  float* d2 = s2 + N;                      // N, becomes z2 after attn2
  __half* wbuf2 = wbuf;                    // E halves

  const int EB = (E + 255) / 256;

  // CSR build
  hipMemsetAsync(deg, 0, (size_t)N * 4, stream);
  hist_kernel<<<EB, 256, 0, stream>>>(dst, deg, E);
  scan_kernel<<<1, 1024, 0, stream>>>(deg, row_start, N);
  hipMemsetAsync(deg, 0, (size_t)N * 4, stream);
  fill_kernel<<<EB, 256, 0, stream>>>(src, dst, row_start, deg, src_sorted, E);

  // Layer 1
  gemm1_kernel<<<(N + 15) / 16, 128, 0, stream>>>(x, W1, a_src1, a_dst1, h1, s1, d1, N);
  attn1_kernel<<<(N + 3) / 4, 256, 0, stream>>>(row_start, src_sorted, s1, d1, wbuf, N);
  agg1_kernel<<<N, 128, 0, stream>>>(row_start, src_sorted, wbuf, d1, h1, b1, x2);

  // Layer 2
  gemm2_kernel<<<(N + 15) / 16, 64, 0, stream>>>(x2, W2, a_src2, a_dst2, h2, s2, d2, N);
  attn2_kernel<<<(N + 3) / 4, 256, 0, stream>>>(row_start, src_sorted, s2, d2, wbuf2, N);
  agg2_kernel<<<N, 64, 0, stream>>>(row_start, src_sorted, wbuf2, d2, h2, b2, out);
}

// Round 4
// 293.167 us; speedup vs baseline: 4.6788x; 1.3132x over previous
//
#include <hip/hip_runtime.h>
#include <hip/hip_fp16.h>

#define INCH   128
#define HEADS1 8
#define HID1   16
#define C1     128   // HEADS1*HID1
#define C2     64
#define NEG_SLOPE 0.2f
#define SB     256   // scan blocks / threads

__device__ __forceinline__ float lrelu(float v) { return v >= 0.f ? v : NEG_SLOPE * v; }

// ---------------- CSR build (by destination) ----------------

__global__ void hist_kernel(const int* __restrict__ dst, int* __restrict__ deg, int E) {
  int e = blockIdx.x * blockDim.x + threadIdx.x;
  if (e < E) atomicAdd(&deg[dst[e]], 1);
}

// stage 1: per-block chunk reduction
__global__ void scan1_kernel(const int* __restrict__ deg, int* __restrict__ partial, int N) {
  __shared__ int sh[SB];
  const int b = blockIdx.x, t = threadIdx.x;
  const int chunk = (N + SB - 1) / SB;
  const int lo = b * chunk, hi = min(lo + chunk, N);
  int s = 0;
  for (int i = lo + t; i < hi; i += SB) s += deg[i];
  sh[t] = s;
  __syncthreads();
  for (int off = SB / 2; off; off >>= 1) {
    if (t < off) sh[t] += sh[t + off];
    __syncthreads();
  }
  if (t == 0) partial[b] = sh[0];
}

// stage 2: exclusive scan of the SB partials (single tiny block)
__global__ void scan2_kernel(int* __restrict__ partial) {
  __shared__ int sh[SB];
  const int t = threadIdx.x;
  int v = partial[t];
  sh[t] = v;
  __syncthreads();
  for (int off = 1; off < SB; off <<= 1) {
    int u = (t >= off) ? sh[t - off] : 0;
    __syncthreads();
    sh[t] += u;
    __syncthreads();
  }
  partial[t] = sh[t] - v;  // exclusive
}

// stage 3: per-block chunk scan with global offset -> row_start[0..N]
__global__ void scan3_kernel(const int* __restrict__ deg, const int* __restrict__ partial,
                             int* __restrict__ row_start, int N) {
  __shared__ int sh[SB];
  const int b = blockIdx.x, t = threadIdx.x;
  const int chunk = (N + SB - 1) / SB;
  const int lo = b * chunk, hi = min(lo + chunk, N);
  int run = partial[b];
  for (int base = lo; base < hi; base += SB) {
    int i = base + t;
    int v = (i < hi) ? deg[i] : 0;
    sh[t] = v;
    __syncthreads();
    for (int off = 1; off < SB; off <<= 1) {
      int u = (t >= off) ? sh[t - off] : 0;
      __syncthreads();
      sh[t] += u;
      __syncthreads();
    }
    if (i < hi) row_start[i] = run + sh[t] - v;  // exclusive
    run += sh[SB - 1];
    __syncthreads();
  }
  if (b == SB - 1 && t == 0) row_start[N] = run;  // total == E
}

__global__ void fill_kernel(const int* __restrict__ src, const int* __restrict__ dst,
                            const int* __restrict__ row_start, int* __restrict__ cursor,
                            int* __restrict__ src_sorted, int E) {
  int e = blockIdx.x * blockDim.x + threadIdx.x;
  if (e >= E) return;
  int d = dst[e];
  int slot = row_start[d] + atomicAdd(&cursor[d], 1);
  src_sorted[slot] = src[e];
}

// ---------------- GEMMs (16 nodes per block; h outputs stored fp16) ----------------

__global__ void gemm1_kernel(const float* __restrict__ x, const float* __restrict__ W1,
                             const float* __restrict__ a_src, const float* __restrict__ a_dst,
                             __half* __restrict__ h1, float* __restrict__ s1, float* __restrict__ d1,
                             int N) {
  __shared__ float xs[16][INCH];
  const int n0 = blockIdx.x * 16;
  const int j = threadIdx.x;  // 0..127
#pragma unroll
  for (int i = 0; i < 16; ++i) {
    int n = n0 + i;
    if (n < N) xs[i][j] = x[(size_t)n * INCH + j];
  }
  __syncthreads();
  float acc[16];
#pragma unroll
  for (int i = 0; i < 16; ++i) acc[i] = 0.f;
  for (int k = 0; k < INCH; k += 4) {
    float w0 = W1[(k + 0) * C1 + j];
    float w1 = W1[(k + 1) * C1 + j];
    float w2 = W1[(k + 2) * C1 + j];
    float w3 = W1[(k + 3) * C1 + j];
#pragma unroll
    for (int i = 0; i < 16; ++i) {
      float4 xv = *(const float4*)&xs[i][k];
      acc[i] += xv.x * w0 + xv.y * w1 + xv.z * w2 + xv.w * w3;
    }
  }
  const int h = j >> 4, c = j & 15;
  const float as = a_src[h * HID1 + c], ad = a_dst[h * HID1 + c];
#pragma unroll
  for (int i = 0; i < 16; ++i) {
    int n = n0 + i;
    if (n >= N) break;
    h1[(size_t)n * C1 + j] = __float2half(acc[i]);
    float sv = acc[i] * as, dv = acc[i] * ad;
#pragma unroll
    for (int off = 8; off; off >>= 1) {
      sv += __shfl_down(sv, off, 16);
      dv += __shfl_down(dv, off, 16);
    }
    if (c == 0) { s1[n * HEADS1 + h] = sv; d1[n * HEADS1 + h] = dv; }
  }
}

__global__ void gemm2_kernel(const float* __restrict__ x2, const float* __restrict__ W2,
                             const float* __restrict__ a_src, const float* __restrict__ a_dst,
                             __half* __restrict__ h2, float* __restrict__ s2, float* __restrict__ d2,
                             int N) {
  __shared__ float xs[16][C1];
  const int n0 = blockIdx.x * 16;
  const int j = threadIdx.x;  // 0..63
#pragma unroll
  for (int i = 0; i < 16; ++i) {
    int n = n0 + i;
    if (n < N) {
      xs[i][j] = x2[(size_t)n * C1 + j];
      xs[i][j + 64] = x2[(size_t)n * C1 + 64 + j];
    }
  }
  __syncthreads();
  float acc[16];
#pragma unroll
  for (int i = 0; i < 16; ++i) acc[i] = 0.f;
  for (int k = 0; k < C1; k += 4) {
    float w0 = W2[(k + 0) * C2 + j];
    float w1 = W2[(k + 1) * C2 + j];
    float w2v = W2[(k + 2) * C2 + j];
    float w3 = W2[(k + 3) * C2 + j];
#pragma unroll
    for (int i = 0; i < 16; ++i) {
      float4 xv = *(const float4*)&xs[i][k];
      acc[i] += xv.x * w0 + xv.y * w1 + xv.z * w2v + xv.w * w3;
    }
  }
  const float as = a_src[j], ad = a_dst[j];
#pragma unroll
  for (int i = 0; i < 16; ++i) {
    int n = n0 + i;
    if (n >= N) break;
    h2[(size_t)n * C2 + j] = __float2half(acc[i]);
    float sv = acc[i] * as, dv = acc[i] * ad;
#pragma unroll
    for (int off = 32; off; off >>= 1) {
      sv += __shfl_down(sv, off);
      dv += __shfl_down(dv, off);
    }
    if (j == 0) { s2[n] = sv; d2[n] = dv; }
  }
}

// ---------------- Attention weights (wave per node) ----------------

__global__ void attn1_kernel(const int* __restrict__ row_start, const int* __restrict__ src_sorted,
                             const float* __restrict__ s1, float* d1z,
                             __half* __restrict__ wbuf, int N) {
  const int wave = threadIdx.x >> 6;
  const int n = blockIdx.x * 4 + wave;
  if (n >= N) return;
  const int lane = threadIdx.x & 63;
  const int le = lane >> 3, h = lane & 7;   // 8 edge-slots x 8 heads
  const int lo = row_start[n], hi = row_start[n + 1];
  const float dv = d1z[n * HEADS1 + h];
  float m = -INFINITY;
  for (int i = lo + le; i < hi; i += 8)
    m = fmaxf(m, lrelu(s1[src_sorted[i] * HEADS1 + h] + dv));
#pragma unroll
  for (int off = 8; off < 64; off <<= 1) m = fmaxf(m, __shfl_xor(m, off));
  if (!isfinite(m)) m = 0.f;
  float z = 0.f;
  for (int i = lo + le; i < hi; i += 8) {
    float w = __expf(lrelu(s1[src_sorted[i] * HEADS1 + h] + dv) - m);
    wbuf[(size_t)i * HEADS1 + h] = __float2half(w);
    z += w;
  }
#pragma unroll
  for (int off = 8; off < 64; off <<= 1) z += __shfl_xor(z, off);
  if (le == 0) d1z[n * HEADS1 + h] = z;
}

__global__ void attn2_kernel(const int* __restrict__ row_start, const int* __restrict__ src_sorted,
                             const float* __restrict__ s2, float* d2z,
                             __half* __restrict__ wbuf2, int N) {
  const int wave = threadIdx.x >> 6;
  const int n = blockIdx.x * 4 + wave;
  if (n >= N) return;
  const int lane = threadIdx.x & 63;
  const int lo = row_start[n], hi = row_start[n + 1];
  const float dv = d2z[n];
  float m = -INFINITY;
  for (int i = lo + lane; i < hi; i += 64)
    m = fmaxf(m, lrelu(s2[src_sorted[i]] + dv));
#pragma unroll
  for (int off = 1; off < 64; off <<= 1) m = fmaxf(m, __shfl_xor(m, off));
  if (!isfinite(m)) m = 0.f;
  float z = 0.f;
  for (int i = lo + lane; i < hi; i += 64) {
    float w = __expf(lrelu(s2[src_sorted[i]] + dv) - m);
    wbuf2[i] = __float2half(w);
    z += w;
  }
#pragma unroll
  for (int off = 1; off < 64; off <<= 1) z += __shfl_xor(z, off);
  if (lane == 0) d2z[n] = z;
}

// ---------------- Weighted aggregation (pure gather, fp16 features) ----------------

__global__ void agg1_kernel(const int* __restrict__ row_start, const int* __restrict__ src_sorted,
                            const __half* __restrict__ wbuf, const float* __restrict__ z1n,
                            const __half* __restrict__ h1, const float* __restrict__ b1,
                            float* __restrict__ x2) {
  const int n = blockIdx.x;
  const int j = threadIdx.x;  // 0..127
  const int h = j >> 4;
  const int lo = row_start[n], hi = row_start[n + 1];
  const float zinv = 1.f / (z1n[n * HEADS1 + h] + 1e-16f);
  float acc = 0.f;
  int i = lo;
  for (; i + 4 <= hi; i += 4) {
    int s0 = src_sorted[i], s1i = src_sorted[i + 1], s2i = src_sorted[i + 2], s3i = src_sorted[i + 3];
    float w0 = __half2float(wbuf[(size_t)(i + 0) * HEADS1 + h]);
    float w1 = __half2float(wbuf[(size_t)(i + 1) * HEADS1 + h]);
    float w2 = __half2float(wbuf[(size_t)(i + 2) * HEADS1 + h]);
    float w3 = __half2float(wbuf[(size_t)(i + 3) * HEADS1 + h]);
    acc += w0 * __half2float(h1[(size_t)s0 * C1 + j]);
    acc += w1 * __half2float(h1[(size_t)s1i * C1 + j]);
    acc += w2 * __half2float(h1[(size_t)s2i * C1 + j]);
    acc += w3 * __half2float(h1[(size_t)s3i * C1 + j]);
  }
  for (; i < hi; ++i)
    acc += __half2float(wbuf[(size_t)i * HEADS1 + h]) * __half2float(h1[(size_t)src_sorted[i] * C1 + j]);
  float o = acc * zinv + b1[j];
  x2[(size_t)n * C1 + j] = o > 0.f ? o : expm1f(o);
}

__global__ void agg2_kernel(const int* __restrict__ row_start, const int* __restrict__ src_sorted,
                            const __half* __restrict__ wbuf2, const float* __restrict__ z2n,
                            const __half* __restrict__ h2, const float* __restrict__ b2,
                            float* __restrict__ out) {
  const int n = blockIdx.x;
  const int j = threadIdx.x;  // 0..63
  const int lo = row_start[n], hi = row_start[n + 1];
  const float zinv = 1.f / (z2n[n] + 1e-16f);
  float acc = 0.f;
  int i = lo;
  for (; i + 4 <= hi; i += 4) {
    int s0 = src_sorted[i], s1i = src_sorted[i + 1], s2i = src_sorted[i + 2], s3i = src_sorted[i + 3];
    float w0 = __half2float(wbuf2[i + 0]);
    float w1 = __half2float(wbuf2[i + 1]);
    float w2 = __half2float(wbuf2[i + 2]);
    float w3 = __half2float(wbuf2[i + 3]);
    acc += w0 * __half2float(h2[(size_t)s0 * C2 + j]);
    acc += w1 * __half2float(h2[(size_t)s1i * C2 + j]);
    acc += w2 * __half2float(h2[(size_t)s2i * C2 + j]);
    acc += w3 * __half2float(h2[(size_t)s3i * C2 + j]);
  }
  for (; i < hi; ++i)
    acc += __half2float(wbuf2[i]) * __half2float(h2[(size_t)src_sorted[i] * C2 + j]);
  out[(size_t)n * C2 + j] = acc * zinv + b2[j];
}

extern "C" void kernel_launch(void* const* d_in, const int* in_sizes, int n_in,
                              void* d_out, int out_size, void* d_ws, size_t ws_size,
                              hipStream_t stream) {
  const float* x      = (const float*)d_in[0];
  const int*   ei     = (const int*)d_in[1];
  const float* W1     = (const float*)d_in[2];
  const float* a_src1 = (const float*)d_in[3];
  const float* a_dst1 = (const float*)d_in[4];
  const float* b1     = (const float*)d_in[5];
  const float* W2     = (const float*)d_in[6];
  const float* a_src2 = (const float*)d_in[7];
  const float* a_dst2 = (const float*)d_in[8];
  const float* b2     = (const float*)d_in[9];
  float* out = (float*)d_out;

  const int N = in_sizes[0] / INCH;
  const int E = in_sizes[1] / 2;
  const int* src = ei;
  const int* dst = ei + E;

  // Workspace layout (~58 MB)
  float* ws = (float*)d_ws;
  size_t o = 0;
  __half* h1 = (__half*)(ws + o); o += (size_t)N * C1 / 2;   // fp16 features (layer1)
  float*  x2 = ws + o;            o += (size_t)N * C1;       // layer-2 input (fp32)
  float*  s1 = ws + o;            o += (size_t)N * HEADS1;
  float*  d1 = ws + o;            o += (size_t)N * HEADS1;   // becomes z1 after attn1
  __half* wbuf = (__half*)(ws + o); o += (size_t)E * HEADS1 / 2;
  int* deg        = (int*)(ws + o); o += N;                  // reused as cursor
  int* row_start  = (int*)(ws + o); o += N + 1;
  int* partial    = (int*)(ws + o); o += SB;
  int* src_sorted = (int*)(ws + o); o += E;
  // layer-2 aliases into h1's region (h1 dead after agg1): 6.4MB + 0.4MB <= 12.8MB
  __half* h2 = h1;                                   // N*64 halves
  float*  s2 = (float*)(h1 + (size_t)N * C2);        // N floats
  float*  d2 = s2 + N;                               // N floats, becomes z2
  __half* wbuf2 = wbuf;                              // E halves

  const int EB = (E + 255) / 256;

  // CSR build
  hipMemsetAsync(deg, 0, (size_t)N * 4, stream);
  hist_kernel<<<EB, 256, 0, stream>>>(dst, deg, E);
  scan1_kernel<<<SB, SB, 0, stream>>>(deg, partial, N);
  scan2_kernel<<<1, SB, 0, stream>>>(partial);
  scan3_kernel<<<SB, SB, 0, stream>>>(deg, partial, row_start, N);
  hipMemsetAsync(deg, 0, (size_t)N * 4, stream);
  fill_kernel<<<EB, 256, 0, stream>>>(src, dst, row_start, deg, src_sorted, E);

  // Layer 1
  gemm1_kernel<<<(N + 15) / 16, 128, 0, stream>>>(x, W1, a_src1, a_dst1, h1, s1, d1, N);
  attn1_kernel<<<(N + 3) / 4, 256, 0, stream>>>(row_start, src_sorted, s1, d1, wbuf, N);
  agg1_kernel<<<N, 128, 0, stream>>>(row_start, src_sorted, wbuf, d1, h1, b1, x2);

  // Layer 2
  gemm2_kernel<<<(N + 15) / 16, 64, 0, stream>>>(x2, W2, a_src2, a_dst2, h2, s2, d2, N);
  attn2_kernel<<<(N + 3) / 4, 256, 0, stream>>>(row_start, src_sorted, s2, d2, wbuf2, N);
  agg2_kernel<<<N, 64, 0, stream>>>(row_start, src_sorted, wbuf2, d2, h2, b2, out);
}

// Round 5
// 248.112 us; speedup vs baseline: 5.5285x; 1.1816x over previous
//
#include <hip/hip_runtime.h>
#include <hip/hip_fp16.h>

#define INCH   128
#define HEADS1 8
#define HID1   16
#define C1     128   // HEADS1*HID1
#define C2     64
#define NEG_SLOPE 0.2f
#define SB     256   // scan blocks / threads

using f16x8 = __attribute__((ext_vector_type(8))) _Float16;
using f32x4 = __attribute__((ext_vector_type(4))) float;

__device__ __forceinline__ float lrelu(float v) { return v >= 0.f ? v : NEG_SLOPE * v; }
// byte-offset swizzle within a 256B LDS row (rows are 128 fp16)
__device__ __forceinline__ int swzA(int row, int byteInRow) {
  return (row << 8) | (byteInRow ^ ((row & 15) << 4));
}

// ---------------- prep: fp32 -> fp16 conversions ----------------

__global__ void cvt_fp16(const float* __restrict__ in, __half* __restrict__ o, int total8) {
  int i = blockIdx.x * blockDim.x + threadIdx.x;
  if (i >= total8) return;
  const float4* p = (const float4*)in + (size_t)i * 2;
  float4 v0 = p[0], v1 = p[1];
  __half2 ha = __floats2half2_rn(v0.x, v0.y);
  __half2 hb = __floats2half2_rn(v0.z, v0.w);
  __half2 hc = __floats2half2_rn(v1.x, v1.y);
  __half2 hd = __floats2half2_rn(v1.z, v1.w);
  uint4 w = { *(unsigned*)&ha, *(unsigned*)&hb, *(unsigned*)&hc, *(unsigned*)&hd };
  ((uint4*)o)[i] = w;
}

// W[K][Ncol] (row-major fp32) -> Wt[Ncol][K] (fp16)
__global__ void transpose_fp16(const float* __restrict__ W, __half* __restrict__ Wt,
                               int K, int Ncol) {
  int id = blockIdx.x * blockDim.x + threadIdx.x;
  if (id >= K * Ncol) return;
  int col = id / K, k = id % K;
  Wt[id] = __float2half(W[k * Ncol + col]);
}

// ---------------- CSR build (by destination) ----------------

__global__ void hist_kernel(const int* __restrict__ dst, int* __restrict__ deg, int E) {
  int e = blockIdx.x * blockDim.x + threadIdx.x;
  if (e < E) atomicAdd(&deg[dst[e]], 1);
}

__global__ void scan1_kernel(const int* __restrict__ deg, int* __restrict__ partial, int N) {
  __shared__ int sh[SB];
  const int b = blockIdx.x, t = threadIdx.x;
  const int chunk = (N + SB - 1) / SB;
  const int lo = b * chunk, hi = min(lo + chunk, N);
  int s = 0;
  for (int i = lo + t; i < hi; i += SB) s += deg[i];
  sh[t] = s;
  __syncthreads();
  for (int off = SB / 2; off; off >>= 1) {
    if (t < off) sh[t] += sh[t + off];
    __syncthreads();
  }
  if (t == 0) partial[b] = sh[0];
}

__global__ void scan2_kernel(int* __restrict__ partial) {
  __shared__ int sh[SB];
  const int t = threadIdx.x;
  int v = partial[t];
  sh[t] = v;
  __syncthreads();
  for (int off = 1; off < SB; off <<= 1) {
    int u = (t >= off) ? sh[t - off] : 0;
    __syncthreads();
    sh[t] += u;
    __syncthreads();
  }
  partial[t] = sh[t] - v;
}

__global__ void scan3_kernel(const int* __restrict__ deg, const int* __restrict__ partial,
                             int* __restrict__ row_start, int N) {
  __shared__ int sh[SB];
  const int b = blockIdx.x, t = threadIdx.x;
  const int chunk = (N + SB - 1) / SB;
  const int lo = b * chunk, hi = min(lo + chunk, N);
  int run = partial[b];
  for (int base = lo; base < hi; base += SB) {
    int i = base + t;
    int v = (i < hi) ? deg[i] : 0;
    sh[t] = v;
    __syncthreads();
    for (int off = 1; off < SB; off <<= 1) {
      int u = (t >= off) ? sh[t - off] : 0;
      __syncthreads();
      sh[t] += u;
      __syncthreads();
    }
    if (i < hi) row_start[i] = run + sh[t] - v;
    run += sh[SB - 1];
    __syncthreads();
  }
  if (b == SB - 1 && t == 0) row_start[N] = run;
}

__global__ void fill_kernel(const int* __restrict__ src, const int* __restrict__ dst,
                            const int* __restrict__ row_start, int* __restrict__ cursor,
                            int* __restrict__ src_sorted, int E) {
  int e = blockIdx.x * blockDim.x + threadIdx.x;
  if (e >= E) return;
  int d = dst[e];
  int slot = row_start[d] + atomicAdd(&cursor[d], 1);
  src_sorted[slot] = src[e];
}

// ---------------- MFMA GEMMs ----------------
// gemm1: [M x 128] x [128 x 128]; 256 thr = 4 waves; block does 64 rows x 128 cols.
__global__ __launch_bounds__(256) void gemm1_mfma(
    const __half* __restrict__ xh, const __half* __restrict__ W1t,
    const float* __restrict__ a_src, const float* __restrict__ a_dst,
    __half* __restrict__ h1, float* __restrict__ s1, float* __restrict__ d1, int M) {
  __shared__ unsigned char As[16384];   // 64 x 128 fp16, swizzled
  __shared__ unsigned char Bs[32768];   // 128 x 128 fp16 (col-major W1), swizzled
  const int t = threadIdx.x;
  const int m0 = blockIdx.x * 64;
  for (int c = t; c < 1024; c += 256) {
    int row = c >> 4, seg = c & 15;
    int gr = m0 + row;
    uint4 v = make_uint4(0, 0, 0, 0);
    if (gr < M) v = ((const uint4*)xh)[(size_t)gr * 16 + seg];
    *(uint4*)(As + swzA(row, seg << 4)) = v;
  }
  for (int c = t; c < 2048; c += 256) {
    int row = c >> 4, seg = c & 15;
    uint4 v = ((const uint4*)W1t)[(row << 4) + seg];
    *(uint4*)(Bs + swzA(row, seg << 4)) = v;
  }
  __syncthreads();
  const int l = t & 63, wid = t >> 6;
  const int c16 = l & 15;                 // col / row-low nibble
  const int kOff = (l >> 4) << 4;         // byte offset of this lane's 8 k-elems
  const int rA = (wid << 4) | c16;
  f16x8 a[4];
#pragma unroll
  for (int kb = 0; kb < 4; ++kb)
    a[kb] = *(const f16x8*)(As + swzA(rA, (kb << 6) + kOff));
#pragma unroll
  for (int ct = 0; ct < 8; ++ct) {        // ct == head (HID1 == 16)
    const int rB = (ct << 4) | c16;
    f32x4 acc = {0.f, 0.f, 0.f, 0.f};
#pragma unroll
    for (int kb = 0; kb < 4; ++kb) {
      f16x8 b = *(const f16x8*)(Bs + swzA(rB, (kb << 6) + kOff));
      acc = __builtin_amdgcn_mfma_f32_16x16x32_f16(a[kb], b, acc, 0, 0, 0);
    }
    const int colg = (ct << 4) + c16;
    const float asv = a_src[colg], adv = a_dst[colg];
#pragma unroll
    for (int i = 0; i < 4; ++i) {
      const int n = m0 + (wid << 4) + ((l >> 4) << 2) + i;
      float v = acc[i];
      float sv = v * asv, dv = v * adv;
      sv += __shfl_xor(sv, 1); sv += __shfl_xor(sv, 2);
      sv += __shfl_xor(sv, 4); sv += __shfl_xor(sv, 8);
      dv += __shfl_xor(dv, 1); dv += __shfl_xor(dv, 2);
      dv += __shfl_xor(dv, 4); dv += __shfl_xor(dv, 8);
      if (n < M) {
        h1[(size_t)n * C1 + colg] = __float2half(v);
        if (c16 == 0) { s1[n * HEADS1 + ct] = sv; d1[n * HEADS1 + ct] = dv; }
      }
    }
  }
}

// gemm2: [M x 128] x [128 x 64]
__global__ __launch_bounds__(256) void gemm2_mfma(
    const __half* __restrict__ x2h, const __half* __restrict__ W2t,
    const float* __restrict__ a_src, const float* __restrict__ a_dst,
    __half* __restrict__ h2, float* __restrict__ s2, float* __restrict__ d2, int M) {
  __shared__ unsigned char As[16384];   // 64 x 128 fp16
  __shared__ unsigned char Bs[16384];   // 64 x 128 fp16 (col-major W2)
  const int t = threadIdx.x;
  const int m0 = blockIdx.x * 64;
  for (int c = t; c < 1024; c += 256) {
    int row = c >> 4, seg = c & 15;
    int gr = m0 + row;
    uint4 v = make_uint4(0, 0, 0, 0);
    if (gr < M) v = ((const uint4*)x2h)[(size_t)gr * 16 + seg];
    *(uint4*)(As + swzA(row, seg << 4)) = v;
  }
  for (int c = t; c < 1024; c += 256) {
    int row = c >> 4, seg = c & 15;
    uint4 v = ((const uint4*)W2t)[(row << 4) + seg];
    *(uint4*)(Bs + swzA(row, seg << 4)) = v;
  }
  __syncthreads();
  const int l = t & 63, wid = t >> 6;
  const int c16 = l & 15;
  const int kOff = (l >> 4) << 4;
  const int rA = (wid << 4) | c16;
  f16x8 a[4];
#pragma unroll
  for (int kb = 0; kb < 4; ++kb)
    a[kb] = *(const f16x8*)(As + swzA(rA, (kb << 6) + kOff));
  float svp[4] = {0.f, 0.f, 0.f, 0.f};
  float dvp[4] = {0.f, 0.f, 0.f, 0.f};
#pragma unroll
  for (int ct = 0; ct < 4; ++ct) {
    const int rB = (ct << 4) | c16;
    f32x4 acc = {0.f, 0.f, 0.f, 0.f};
#pragma unroll
    for (int kb = 0; kb < 4; ++kb) {
      f16x8 b = *(const f16x8*)(Bs + swzA(rB, (kb << 6) + kOff));
      acc = __builtin_amdgcn_mfma_f32_16x16x32_f16(a[kb], b, acc, 0, 0, 0);
    }
    const int colg = (ct << 4) + c16;
    const float asv = a_src[colg], adv = a_dst[colg];
#pragma unroll
    for (int i = 0; i < 4; ++i) {
      const int n = m0 + (wid << 4) + ((l >> 4) << 2) + i;
      float v = acc[i];
      svp[i] += v * asv;
      dvp[i] += v * adv;
      if (n < M) h2[(size_t)n * C2 + colg] = __float2half(v);
    }
  }
#pragma unroll
  for (int i = 0; i < 4; ++i) {
    float sv = svp[i], dv = dvp[i];
    sv += __shfl_xor(sv, 1); sv += __shfl_xor(sv, 2);
    sv += __shfl_xor(sv, 4); sv += __shfl_xor(sv, 8);
    dv += __shfl_xor(dv, 1); dv += __shfl_xor(dv, 2);
    dv += __shfl_xor(dv, 4); dv += __shfl_xor(dv, 8);
    const int n = m0 + (wid << 4) + ((l >> 4) << 2) + i;
    if (c16 == 0 && n < M) { s2[n] = sv; d2[n] = dv; }
  }
}

// ---------------- Attention weights (wave per node) ----------------

__global__ void attn1_kernel(const int* __restrict__ row_start, const int* __restrict__ src_sorted,
                             const float* __restrict__ s1, float* d1z,
                             __half* __restrict__ wbuf, int N) {
  const int wave = threadIdx.x >> 6;
  const int n = blockIdx.x * 4 + wave;
  if (n >= N) return;
  const int lane = threadIdx.x & 63;
  const int le = lane >> 3, h = lane & 7;
  const int lo = row_start[n], hi = row_start[n + 1];
  const float dv = d1z[n * HEADS1 + h];
  float m = -INFINITY;
  for (int i = lo + le; i < hi; i += 8)
    m = fmaxf(m, lrelu(s1[src_sorted[i] * HEADS1 + h] + dv));
#pragma unroll
  for (int off = 8; off < 64; off <<= 1) m = fmaxf(m, __shfl_xor(m, off));
  if (!isfinite(m)) m = 0.f;
  float z = 0.f;
  for (int i = lo + le; i < hi; i += 8) {
    float w = __expf(lrelu(s1[src_sorted[i] * HEADS1 + h] + dv) - m);
    wbuf[(size_t)i * HEADS1 + h] = __float2half(w);
    z += w;
  }
#pragma unroll
  for (int off = 8; off < 64; off <<= 1) z += __shfl_xor(z, off);
  if (le == 0) d1z[n * HEADS1 + h] = z;
}

__global__ void attn2_kernel(const int* __restrict__ row_start, const int* __restrict__ src_sorted,
                             const float* __restrict__ s2, float* d2z,
                             __half* __restrict__ wbuf2, int N) {
  const int wave = threadIdx.x >> 6;
  const int n = blockIdx.x * 4 + wave;
  if (n >= N) return;
  const int lane = threadIdx.x & 63;
  const int lo = row_start[n], hi = row_start[n + 1];
  const float dv = d2z[n];
  float m = -INFINITY;
  for (int i = lo + lane; i < hi; i += 64)
    m = fmaxf(m, lrelu(s2[src_sorted[i]] + dv));
#pragma unroll
  for (int off = 1; off < 64; off <<= 1) m = fmaxf(m, __shfl_xor(m, off));
  if (!isfinite(m)) m = 0.f;
  float z = 0.f;
  for (int i = lo + lane; i < hi; i += 64) {
    float w = __expf(lrelu(s2[src_sorted[i]] + dv) - m);
    wbuf2[i] = __float2half(w);
    z += w;
  }
#pragma unroll
  for (int off = 1; off < 64; off <<= 1) z += __shfl_xor(z, off);
  if (lane == 0) d2z[n] = z;
}

// ---------------- Weighted aggregation (pure gather, fp16 features) ----------------

__global__ void agg1_kernel(const int* __restrict__ row_start, const int* __restrict__ src_sorted,
                            const __half* __restrict__ wbuf, const float* __restrict__ z1n,
                            const __half* __restrict__ h1, const float* __restrict__ b1,
                            __half* __restrict__ x2h) {
  const int n = blockIdx.x;
  const int j = threadIdx.x;  // 0..127
  const int h = j >> 4;
  const int lo = row_start[n], hi = row_start[n + 1];
  const float zinv = 1.f / (z1n[n * HEADS1 + h] + 1e-16f);
  float acc = 0.f;
  int i = lo;
  for (; i + 4 <= hi; i += 4) {
    int s0 = src_sorted[i], s1i = src_sorted[i + 1], s2i = src_sorted[i + 2], s3i = src_sorted[i + 3];
    float w0 = __half2float(wbuf[(size_t)(i + 0) * HEADS1 + h]);
    float w1 = __half2float(wbuf[(size_t)(i + 1) * HEADS1 + h]);
    float w2 = __half2float(wbuf[(size_t)(i + 2) * HEADS1 + h]);
    float w3 = __half2float(wbuf[(size_t)(i + 3) * HEADS1 + h]);
    acc += w0 * __half2float(h1[(size_t)s0 * C1 + j]);
    acc += w1 * __half2float(h1[(size_t)s1i * C1 + j]);
    acc += w2 * __half2float(h1[(size_t)s2i * C1 + j]);
    acc += w3 * __half2float(h1[(size_t)s3i * C1 + j]);
  }
  for (; i < hi; ++i)
    acc += __half2float(wbuf[(size_t)i * HEADS1 + h]) * __half2float(h1[(size_t)src_sorted[i] * C1 + j]);
  float o = acc * zinv + b1[j];
  x2h[(size_t)n * C1 + j] = __float2half(o > 0.f ? o : expm1f(o));
}

__global__ void agg2_kernel(const int* __restrict__ row_start, const int* __restrict__ src_sorted,
                            const __half* __restrict__ wbuf2, const float* __restrict__ z2n,
                            const __half* __restrict__ h2, const float* __restrict__ b2,
                            float* __restrict__ out) {
  const int n = blockIdx.x;
  const int j = threadIdx.x;  // 0..63
  const int lo = row_start[n], hi = row_start[n + 1];
  const float zinv = 1.f / (z2n[n] + 1e-16f);
  float acc = 0.f;
  int i = lo;
  for (; i + 4 <= hi; i += 4) {
    int s0 = src_sorted[i], s1i = src_sorted[i + 1], s2i = src_sorted[i + 2], s3i = src_sorted[i + 3];
    float w0 = __half2float(wbuf2[i + 0]);
    float w1 = __half2float(wbuf2[i + 1]);
    float w2 = __half2float(wbuf2[i + 2]);
    float w3 = __half2float(wbuf2[i + 3]);
    acc += w0 * __half2float(h2[(size_t)s0 * C2 + j]);
    acc += w1 * __half2float(h2[(size_t)s1i * C2 + j]);
    acc += w2 * __half2float(h2[(size_t)s2i * C2 + j]);
    acc += w3 * __half2float(h2[(size_t)s3i * C2 + j]);
  }
  for (; i < hi; ++i)
    acc += __half2float(wbuf2[i]) * __half2float(h2[(size_t)src_sorted[i] * C2 + j]);
  out[(size_t)n * C2 + j] = acc * zinv + b2[j];
}

extern "C" void kernel_launch(void* const* d_in, const int* in_sizes, int n_in,
                              void* d_out, int out_size, void* d_ws, size_t ws_size,
                              hipStream_t stream) {
  const float* x      = (const float*)d_in[0];
  const int*   ei     = (const int*)d_in[1];
  const float* W1     = (const float*)d_in[2];
  const float* a_src1 = (const float*)d_in[3];
  const float* a_dst1 = (const float*)d_in[4];
  const float* b1     = (const float*)d_in[5];
  const float* W2     = (const float*)d_in[6];
  const float* a_src2 = (const float*)d_in[7];
  const float* a_dst2 = (const float*)d_in[8];
  const float* b2     = (const float*)d_in[9];
  float* out = (float*)d_out;

  const int N = in_sizes[0] / INCH;
  const int E = in_sizes[1] / 2;
  const int* src = ei;
  const int* dst = ei + E;

  // Workspace layout (~58 MB; >=71 MB proven available in round 1)
  float* ws = (float*)d_ws;
  size_t o = 0;
  __half* xh  = (__half*)(ws + o); o += (size_t)N * C1 / 2;   // x in fp16
  __half* h1  = (__half*)(ws + o); o += (size_t)N * C1 / 2;   // layer-1 features fp16
  __half* x2h = (__half*)(ws + o); o += (size_t)N * C1 / 2;   // layer-2 input fp16
  float*  s1  = ws + o;            o += (size_t)N * HEADS1;
  float*  d1  = ws + o;            o += (size_t)N * HEADS1;   // becomes z1 after attn1
  __half* wbuf = (__half*)(ws + o); o += (size_t)E * HEADS1 / 2;
  __half* W1t = (__half*)(ws + o); o += 128 * 128 / 2;        // W1^T fp16 [128][128]
  __half* W2t = (__half*)(ws + o); o += 64 * 128 / 2;         // W2^T fp16 [64][128]
  int* deg        = (int*)(ws + o); o += N;                   // reused as cursor
  int* row_start  = (int*)(ws + o); o += N + 1;
  int* partial    = (int*)(ws + o); o += SB;
  int* src_sorted = (int*)(ws + o); o += E;
  // layer-2 aliases into h1's region (h1 dead after agg1)
  __half* h2 = h1;                                   // N*64 halves
  float*  s2 = (float*)h1 + (size_t)N * 32;          // N floats (after h2's N*32 floats)
  float*  d2 = s2 + N;                               // N floats, becomes z2
  __half* wbuf2 = wbuf;

  const int EB = (E + 255) / 256;
  const int NB64 = (N + 63) / 64;

  // prep: fp16 conversions
  cvt_fp16<<<(N * C1 / 8 + 255) / 256, 256, 0, stream>>>(x, xh, N * C1 / 8);
  transpose_fp16<<<(128 * 128 + 255) / 256, 256, 0, stream>>>(W1, W1t, 128, 128);
  transpose_fp16<<<(64 * 128 + 255) / 256, 256, 0, stream>>>(W2, W2t, 128, 64);

  // CSR build
  hipMemsetAsync(deg, 0, (size_t)N * 4, stream);
  hist_kernel<<<EB, 256, 0, stream>>>(dst, deg, E);
  scan1_kernel<<<SB, SB, 0, stream>>>(deg, partial, N);
  scan2_kernel<<<1, SB, 0, stream>>>(partial);
  scan3_kernel<<<SB, SB, 0, stream>>>(deg, partial, row_start, N);
  hipMemsetAsync(deg, 0, (size_t)N * 4, stream);
  fill_kernel<<<EB, 256, 0, stream>>>(src, dst, row_start, deg, src_sorted, E);

  // Layer 1
  gemm1_mfma<<<NB64, 256, 0, stream>>>(xh, W1t, a_src1, a_dst1, h1, s1, d1, N);
  attn1_kernel<<<(N + 3) / 4, 256, 0, stream>>>(row_start, src_sorted, s1, d1, wbuf, N);
  agg1_kernel<<<N, 128, 0, stream>>>(row_start, src_sorted, wbuf, d1, h1, b1, x2h);

  // Layer 2
  gemm2_mfma<<<NB64, 256, 0, stream>>>(x2h, W2t, a_src2, a_dst2, h2, s2, d2, N);
  attn2_kernel<<<(N + 3) / 4, 256, 0, stream>>>(row_start, src_sorted, s2, d2, wbuf2, N);
  agg2_kernel<<<N, 64, 0, stream>>>(row_start, src_sorted, wbuf2, d2, h2, b2, out);
}